// Round 12
// baseline (1528.582 us; speedup 1.0000x reference)
//
#include <hip/hip_runtime.h>
#include <hip/hip_fp16.h>
#include <stdint.h>
#include <type_traits>

// ClockworkRNN MI355X round 12.
// R11 (verified, absmax 0.0039) + ONE change: __launch_bounds__(512, 1) on the
// scan. Evidence: every (512,2) round shows VGPR_Count pinned at exactly 128
// (compiler treats arg2 as blocks/CU -> 16-wave -> 128-VGPR cap); R11's
// per-lane dual-column weights (~160 h2 regs on pair0) spilled -> WRITE_SIZE
// 128KB -> 8.3MB + FETCH +4.3MB, masking the LDS-op-halving win. (512,1)
// raises the cap to 256 VGPR; all 8 waves of the single block remain
// co-resident by workgroup contract.
// ws layout (bytes): [0, 67108864) X f16 | [67108864, 67371008) W^T f16 |
//                    [67371008, 100794368) compact x f16.

typedef _Float16 half_t;
typedef _Float16 h2 __attribute__((ext_vector_type(2)));
typedef _Float16 h8 __attribute__((ext_vector_type(8)));
typedef float f4 __attribute__((ext_vector_type(4)));

__device__ __forceinline__ float dot2f(h2 a, h2 b, float c) {
#if defined(__has_builtin)
#if __has_builtin(__builtin_amdgcn_fdot2)
  return __builtin_amdgcn_fdot2(a, b, c, false);
#else
  return c + (float)a[0] * (float)b[0] + (float)a[1] * (float)b[1];
#endif
#else
  return c + (float)a[0] * (float)b[0] + (float)a[1] * (float)b[1];
#endif
}

__device__ __forceinline__ float fast_tanh(float x) {
#if defined(__has_builtin)
#if __has_builtin(__builtin_amdgcn_exp2f) && __has_builtin(__builtin_amdgcn_rcpf)
  float e = __builtin_amdgcn_exp2f(x * 2.885390081777927f);
  return 1.0f - 2.0f * __builtin_amdgcn_rcpf(e + 1.0f);
#else
  float e = __builtin_exp2f(x * 2.885390081777927f);
  return 1.0f - 2.0f / (e + 1.0f);
#endif
#else
  float e = exp2f(x * 2.885390081777927f);
  return 1.0f - 2.0f / (e + 1.0f);
#endif
}

__device__ __forceinline__ float u2f(unsigned short u) {
  return (float)__builtin_bit_cast(half_t, u);
}

// 4-way reduce over {l, l^16, l^32, l^48}: 3 independent gathers, 1 DS hop.
__device__ __forceinline__ float red3(float v) {
  float a = __shfl_xor(v, 16);
  float b = __shfl_xor(v, 32);
  float d = __shfl_xor(v, 48);
  return (v + a) + (b + d);
}

// Relaxed workgroup barrier: orders LDS (lgkm), leaves global loads in flight.
__device__ __forceinline__ void wg_barrier_lds() {
  __builtin_amdgcn_sched_barrier(0);
  asm volatile("s_waitcnt lgkmcnt(0)" ::: "memory");
  __builtin_amdgcn_s_barrier();
  __builtin_amdgcn_sched_barrier(0);
}

__device__ __forceinline__ void gl_lds16(const half_t* g, half_t* l) {
  __builtin_amdgcn_global_load_lds(
      (__attribute__((address_space(1))) void*)(void*)g,
      (__attribute__((address_space(3))) void*)(void*)l, 16, 0, 0);
}

// ---------------- cvt kernels (unchanged, verified) ----------------
__global__ void cw_cvt_x(const float* __restrict__ X, half_t* __restrict__ Xh, long n4) {
  long i = (long)blockIdx.x * blockDim.x + threadIdx.x;
  const long stride = (long)gridDim.x * blockDim.x;
  const float4* X4 = (const float4*)X;
  h2* out2 = (h2*)Xh;
  for (; i < n4; i += stride) {
    float4 v = X4[i];
    h2 a; a[0] = (half_t)v.x; a[1] = (half_t)v.y;
    h2 b; b[0] = (half_t)v.z; b[1] = (half_t)v.w;
    out2[2 * i] = a;
    out2[2 * i + 1] = b;
  }
}

__global__ void cw_cvt_wt(const float* __restrict__ W, half_t* __restrict__ WT) {
  int idx = blockIdx.x * 256 + threadIdx.x;  // 131072 total
  int o = idx >> 8, d = idx & 255;
  WT[idx] = (half_t)W[d * 512 + o];
}

// ---------------- x projection (unchanged, verified) ----------------
__global__ __launch_bounds__(256) void cw_xproj(const half_t* __restrict__ Xh,
                                                const half_t* __restrict__ WT,
                                                const float* __restrict__ bias,
                                                half_t* __restrict__ xout) {
  const int mod = blockIdx.y;
  const int Ti = 2048 >> mod;
  const long Mi = (long)64 * Ti;
  const long m0r = (long)blockIdx.x * 256;
  if (m0r >= Mi) return;
  __shared__ alignas(16) half_t Bs[64 * 256];
  __shared__ alignas(16) half_t As[256 * 64];
  const int tid = threadIdx.x;
  const int wv = tid >> 6, l = tid & 63;
  const int lr = l & 15, lk = (l >> 4) * 8;
  const int shf = 11 - mod;

#pragma unroll
  for (int it = 0; it < 8; ++it) {
    int slot = it * 256 + tid;
    int n = slot >> 5, kc = slot & 31;
    gl_lds16(WT + ((mod << 6) + n) * 256 + kc * 8, Bs + slot * 8);
  }

  f4 acc[4][4];
#pragma unroll
  for (int a = 0; a < 4; ++a)
#pragma unroll
    for (int bq = 0; bq < 4; ++bq) acc[a][bq] = f4{0.f, 0.f, 0.f, 0.f};

  for (int kt = 0; kt < 4; ++kt) {
#pragma unroll
    for (int it = 0; it < 8; ++it) {
      int slot = it * 256 + tid;
      int r = slot >> 3, kc = slot & 7;
      long m = m0r + r;
      long g = (m >> shf) * 2048 + ((m & (long)(Ti - 1)) << mod);
      gl_lds16(Xh + g * 256 + kt * 64 + kc * 8, As + slot * 8);
    }
    __syncthreads();
#pragma unroll
    for (int ks = 0; ks < 2; ++ks) {
      h8 af[4], bf[4];
#pragma unroll
      for (int mi = 0; mi < 4; ++mi)
        af[mi] = *(const h8*)&As[(wv * 64 + mi * 16 + lr) * 64 + ks * 32 + lk];
#pragma unroll
      for (int ni = 0; ni < 4; ++ni)
        bf[ni] = *(const h8*)&Bs[(ni * 16 + lr) * 256 + kt * 64 + ks * 32 + lk];
#pragma unroll
      for (int mi = 0; mi < 4; ++mi)
#pragma unroll
        for (int ni = 0; ni < 4; ++ni)
          acc[mi][ni] = __builtin_amdgcn_mfma_f32_16x16x32_f16(af[mi], bf[ni], acc[mi][ni], 0, 0, 0);
    }
    __syncthreads();
  }

  const long xb = 16777216L - (16777216L >> mod);
#pragma unroll
  for (int ni = 0; ni < 4; ++ni) {
    int n = ni * 16 + lr;
    float bv = bias[(mod << 6) + n];
#pragma unroll
    for (int mi = 0; mi < 4; ++mi) {
      f4 cf = acc[mi][ni];
#pragma unroll
      for (int q = 0; q < 4; ++q) {
        long m = m0r + wv * 64 + mi * 16 + (l >> 4) * 4 + q;
        xout[xb + m * 64 + n] = (half_t)(cf[q] + bv);
      }
    }
  }
}

// ---------------- scan round 12 (R11 + VGPR-cap fix) ----------------
// PAIR p: fast module m_p (period 2^p) on waves {2p,2p+1}; slow module
// S[p] = {m6,m5,m4,m7}[p]. Per lane: 2 cols {colA=32*half+cl, colB=colA+16},
// K-chunk q=l>>4. Owners: l<32 -> fast col ownCol; l>=32 -> slow col ownCol.

template <int PAIR>
__device__ __forceinline__ void scan_role(
    const unsigned short* __restrict__ xb16,
    const float* __restrict__ Wf, const float* __restrict__ Ws,
    float* __restrict__ out, half_t (*hbuf)[512], int b) {
  constexpr int P4Fv[4] = {64, 56, 48, 40};
  constexpr int HBFv[4] = {0, 32, 64, 96};
  constexpr int P4Sv[4] = {16, 24, 32, 8};
  constexpr int HBSv[4] = {192, 160, 128, 224};
  constexpr int SSHv[4] = {6, 5, 4, 7};
  constexpr long FXBv[4] = {0L, 8388608L, 12582912L, 14680064L};
  constexpr long SXBv[4] = {16515072L, 16252928L, 15728640L, 16646144L};
  constexpr int FBASEv[4] = {0, 64, 128, 192};
  constexpr int SBASEv[4] = {384, 320, 256, 448};
  constexpr int P4F = P4Fv[PAIR], HBF = HBFv[PAIR];
  constexpr int P4S = P4Sv[PAIR], HBS = HBSv[PAIR], SSH = SSHv[PAIR];
  constexpr int FB = FBASEv[PAIR], SB = SBASEv[PAIR];
  constexpr int SROWS = 2048 >> SSH;
  constexpr int SMASK = (1 << SSH) - 1;

  const int tid = threadIdx.x;
  const int wv = tid >> 6, l = tid & 63;
  const int half = wv & 1;
  const int q = l >> 4;
  const int cl = l & 15;
  const int colA = 32 * half + cl;
  const int colB = colA + 16;
  const int sg01 = q & 1;
  const bool ownFast = (l < 32);
  const int ownCol = 32 * half + 16 * sg01 + cl;

  // ---- weights (all registers, static indices) ----
  h2 wfA[P4F], wfB[P4F], wsA[P4S], wsB[P4S];
  if constexpr (PAIR == 0) {
    // m0 bank-rotation (R4-verified): wf*[4g+j] <- pair q*64+((g+2q)&15)*4+j
#pragma unroll
    for (int g = 0; g < 16; ++g) {
      const int gg = (g + 2 * q) & 15;
#pragma unroll
      for (int j = 0; j < 4; ++j) {
        int pr = (q << 6) + gg * 4 + j;
        wfA[g * 4 + j] = h2{(half_t)Wf[(2 * pr) * 64 + colA], (half_t)Wf[(2 * pr + 1) * 64 + colA]};
        wfB[g * 4 + j] = h2{(half_t)Wf[(2 * pr) * 64 + colB], (half_t)Wf[(2 * pr + 1) * 64 + colB]};
      }
    }
  } else {
#pragma unroll
    for (int p = 0; p < P4F; ++p) {
      int pr = q * P4F + p;
      wfA[p] = h2{(half_t)Wf[(2 * pr) * 64 + colA], (half_t)Wf[(2 * pr + 1) * 64 + colA]};
      wfB[p] = h2{(half_t)Wf[(2 * pr) * 64 + colB], (half_t)Wf[(2 * pr + 1) * 64 + colB]};
    }
  }
#pragma unroll
  for (int p = 0; p < P4S; ++p) {
    int pr = q * P4S + p;
    wsA[p] = h2{(half_t)Ws[(2 * pr) * 64 + colA], (half_t)Ws[(2 * pr + 1) * 64 + colA]};
    wsB[p] = h2{(half_t)Ws[(2 * pr) * 64 + colB], (half_t)Ws[(2 * pr + 1) * 64 + colB]};
  }

  hbuf[0][tid] = (half_t)0.f;
  hbuf[1][tid] = (half_t)0.f;

  // ---- owner x pointer (fast owners: module m_PAIR; slow owners: S[PAIR]) ----
  const unsigned short* xp = ownFast
      ? (xb16 + FXBv[PAIR] + ((long)b << (17 - PAIR)) + ownCol)
      : (xb16 + SXBv[PAIR] + ((long)b << (17 - SSH)) + ownCol);

  unsigned short xr0 = 0, xr1 = 0, xr2 = 0, xr3 = 0, xrS = 0;
  if (ownFast) {
    xr0 = xp[0];
    if constexpr (PAIR == 0) { xr1 = xp[64]; xr2 = xp[128]; xr3 = xp[192]; }
    if constexpr (PAIR == 1) { xr1 = xp[64]; }
  } else {
    xrS = xp[0];
  }
  float hs = 0.f;
  __syncthreads();

  auto stepf = [&](auto offc, int t, const half_t* hin, half_t* hout) {
    constexpr int OFF = decltype(offc)::value;
    const h2* hin2 = (const h2*)hin;
    constexpr bool FACT = (PAIR == 0) || (PAIR == 1 && (OFF & 1) == 0) ||
                          (PAIR >= 2 && OFF == 0);
    float vA = 0.f, vB = 0.f, vSA = 0.f, vSB = 0.f;
    bool fup = false;
    if constexpr (FACT) {
      if constexpr (PAIR == 3) fup = ((t & 7) == 0);
      else fup = true;
      if (fup) {
        float a0 = 0.f, a1 = 0.f, a2 = 0.f, a3 = 0.f;
        float b0 = 0.f, b1 = 0.f, b2 = 0.f, b3 = 0.f;
        if constexpr (PAIR == 0) {
          const h2* hp = hin2 + (q << 6);
#pragma unroll
          for (int g = 0; g < 16; ++g) {
            const int gg = (g + 2 * q) & 15;  // runtime LDS index only
            h2 h0 = hp[gg * 4 + 0], h1 = hp[gg * 4 + 1];
            h2 h2v = hp[gg * 4 + 2], h3 = hp[gg * 4 + 3];
            a0 = dot2f(h0, wfA[g * 4 + 0], a0); b0 = dot2f(h0, wfB[g * 4 + 0], b0);
            a1 = dot2f(h1, wfA[g * 4 + 1], a1); b1 = dot2f(h1, wfB[g * 4 + 1], b1);
            a2 = dot2f(h2v, wfA[g * 4 + 2], a2); b2 = dot2f(h2v, wfB[g * 4 + 2], b2);
            a3 = dot2f(h3, wfA[g * 4 + 3], a3); b3 = dot2f(h3, wfB[g * 4 + 3], b3);
          }
        } else {
          const h2* hp = hin2 + HBF + q * P4F;
#pragma unroll
          for (int p = 0; p < P4F; p += 4) {
            h2 h0 = hp[p], h1 = hp[p + 1], h2v = hp[p + 2], h3 = hp[p + 3];
            a0 = dot2f(h0, wfA[p + 0], a0); b0 = dot2f(h0, wfB[p + 0], b0);
            a1 = dot2f(h1, wfA[p + 1], a1); b1 = dot2f(h1, wfB[p + 1], b1);
            a2 = dot2f(h2v, wfA[p + 2], a2); b2 = dot2f(h2v, wfB[p + 2], b2);
            a3 = dot2f(h3, wfA[p + 3], a3); b3 = dot2f(h3, wfB[p + 3], b3);
          }
        }
        vA = red3((a0 + a1) + (a2 + a3));
        vB = red3((b0 + b1) + (b2 + b3));
      }
    }
    bool sup = false;
    if constexpr (OFF == 0) {
      sup = ((t & SMASK) == 0);
      if (sup) {
        float a0 = 0.f, a1 = 0.f, a2 = 0.f, a3 = 0.f;
        float b0 = 0.f, b1 = 0.f, b2 = 0.f, b3 = 0.f;
        const h2* hp = hin2 + HBS + q * P4S;
#pragma unroll
        for (int p = 0; p < P4S; p += 4) {
          h2 h0 = hp[p], h1 = hp[p + 1], h2v = hp[p + 2], h3 = hp[p + 3];
          a0 = dot2f(h0, wsA[p + 0], a0); b0 = dot2f(h0, wsB[p + 0], b0);
          a1 = dot2f(h1, wsA[p + 1], a1); b1 = dot2f(h1, wsB[p + 1], b1);
          a2 = dot2f(h2v, wsA[p + 2], a2); b2 = dot2f(h2v, wsB[p + 2], b2);
          a3 = dot2f(h3, wsA[p + 3], a3); b3 = dot2f(h3, wsB[p + 3], b3);
        }
        vSA = red3((a0 + a1) + (a2 + a3));
        vSB = red3((b0 + b1) + (b2 + b3));
      }
    }
    // ---- owner phase: 1 col per lane ----
    bool myUpd = ownFast ? fup : sup;
    float mySum = ownFast ? (sg01 ? vB : vA) : (sg01 ? vSB : vSA);
    float xv;
    if (ownFast) {
      if constexpr (PAIR == 0) {
        if constexpr (OFF == 0) xv = u2f(xr0);
        else if constexpr (OFF == 1) xv = u2f(xr1);
        else if constexpr (OFF == 2) xv = u2f(xr2);
        else xv = u2f(xr3);
      } else if constexpr (PAIR == 1) {
        xv = (OFF == 0) ? u2f(xr0) : u2f(xr1);
      } else {
        xv = u2f(xr0);
      }
    } else {
      xv = u2f(xrS);
    }
    float s = myUpd ? (mySum + xv) : hs;
    hs = fast_tanh(s);
    hout[(ownFast ? FB : SB) + ownCol] = (half_t)hs;
    // ---- ring advance (raw u16; cvt at use) ----
    if (ownFast) {
      if constexpr (PAIR == 0) {
        int tn = t + OFF + 4;
        if (tn < 2048) {
          unsigned short nv = xp[(long)tn << 6];
          if constexpr (OFF == 0) xr0 = nv;
          else if constexpr (OFF == 1) xr1 = nv;
          else if constexpr (OFF == 2) xr2 = nv;
          else xr3 = nv;
        }
      } else if constexpr (PAIR == 1) {
        if constexpr (OFF == 0) {
          int rn = (t >> 1) + 2;
          if (rn < 1024) xr0 = xp[(long)rn << 6];
        } else if constexpr (OFF == 2) {
          int rn = (t >> 1) + 3;
          if (rn < 1024) xr1 = xp[(long)rn << 6];
        }
      } else if constexpr (PAIR == 2) {
        if constexpr (OFF == 0) {
          int ni = (t >> 2) + 1;
          if (ni < 512) xr0 = xp[(long)ni << 6];
        }
      } else {
        if constexpr (OFF == 0) {
          if (fup) {
            int ni = (t >> 3) + 1;
            if (ni < 256) xr0 = xp[(long)ni << 6];
          }
        }
      }
    } else {
      if (sup) {
        int ni = (t >> SSH) + 1;
        if (ni < SROWS) xrS = xp[(long)ni << 6];
      }
    }
    wg_barrier_lds();
  };

  for (int t = 0; t < 2048; t += 4) {
    stepf(std::integral_constant<int, 0>{}, t, hbuf[0], hbuf[1]);
    stepf(std::integral_constant<int, 1>{}, t, hbuf[1], hbuf[0]);
    stepf(std::integral_constant<int, 2>{}, t, hbuf[0], hbuf[1]);
    stepf(std::integral_constant<int, 3>{}, t, hbuf[1], hbuf[0]);
  }

  out[((long)b << 9) + (ownFast ? FB : SB) + ownCol] = hs;
}

__global__ __launch_bounds__(512, 1) void cw_scan12(
    const half_t* __restrict__ xbuf,
    const float* __restrict__ Wc0, const float* __restrict__ Wc1,
    const float* __restrict__ Wc2, const float* __restrict__ Wc3,
    const float* __restrict__ Wc4, const float* __restrict__ Wc5,
    const float* __restrict__ Wc6, const float* __restrict__ Wc7,
    float* __restrict__ out) {
  __shared__ alignas(16) half_t hbuf[2][512];
  const int b = blockIdx.x;
  const unsigned short* xb16 = (const unsigned short*)xbuf;
  const int pair = threadIdx.x >> 7;  // wave>>1
  if (pair == 0) scan_role<0>(xb16, Wc0, Wc6, out, hbuf, b);
  else if (pair == 1) scan_role<1>(xb16, Wc1, Wc5, out, hbuf, b);
  else if (pair == 2) scan_role<2>(xb16, Wc2, Wc4, out, hbuf, b);
  else scan_role<3>(xb16, Wc3, Wc7, out, hbuf, b);
}

// ---------------- launcher ----------------
extern "C" void kernel_launch(void* const* d_in, const int* in_sizes, int n_in,
                              void* d_out, int out_size, void* d_ws, size_t ws_size,
                              hipStream_t stream) {
  const float* X = (const float*)d_in[0];
  const float* W = (const float*)d_in[1];
  const float* bias = (const float*)d_in[2];
  const float* Wc0 = (const float*)d_in[3];
  const float* Wc1 = (const float*)d_in[4];
  const float* Wc2 = (const float*)d_in[5];
  const float* Wc3 = (const float*)d_in[6];
  const float* Wc4 = (const float*)d_in[7];
  const float* Wc5 = (const float*)d_in[8];
  const float* Wc6 = (const float*)d_in[9];
  const float* Wc7 = (const float*)d_in[10];
  float* out = (float*)d_out;

  half_t* Xh = (half_t*)d_ws;                       // 67,108,864 B
  half_t* WT = (half_t*)((char*)d_ws + 67108864);   //    262,144 B
  half_t* xbuf = (half_t*)((char*)d_ws + 67371008); // 33,423,360 B

  cw_cvt_x<<<4096, 256, 0, stream>>>(X, Xh, 8388608L);
  cw_cvt_wt<<<512, 256, 0, stream>>>(W, WT);
  dim3 g(512, 8);
  cw_xproj<<<g, 256, 0, stream>>>(Xh, WT, bias, xbuf);
  cw_scan12<<<64, 512, 0, stream>>>(xbuf, Wc0, Wc1, Wc2, Wc3, Wc4, Wc5, Wc6, Wc7, out);
}

// Round 14
// 1416.375 us; speedup vs baseline: 1.0792x; 1.0792x over previous
//
#include <hip/hip_runtime.h>
#include <hip/hip_fp16.h>
#include <stdint.h>
#include <type_traits>

// ClockworkRNN MI355X round 14.
// R12 (verified, 1507us) + time-major x: xproj writes x as [b][col][t] per
// module; scan owners load 8 update-events per 16B chunk (2x u64, uniform
// shift extract, 2-chunk double buffer) instead of a scattered 2B load per
// update. Kills ~per-step global-load issue + ring bookkeeping on the chain.
// R13 lesson (ERRATA): permlane16/32_swap A=B trick is WRONG on gfx950
// (absmax 1.93, same as R6) -- shfl_xor reduction retained.
// ws layout (bytes): [0, 67108864) X f16 | [67108864, 67371008) W^T f16 |
//                    [67371008, 100794368) compact x f16 (time-major).

typedef _Float16 half_t;
typedef _Float16 h2 __attribute__((ext_vector_type(2)));
typedef _Float16 h8 __attribute__((ext_vector_type(8)));
typedef float f4 __attribute__((ext_vector_type(4)));

__device__ __forceinline__ float dot2f(h2 a, h2 b, float c) {
#if defined(__has_builtin)
#if __has_builtin(__builtin_amdgcn_fdot2)
  return __builtin_amdgcn_fdot2(a, b, c, false);
#else
  return c + (float)a[0] * (float)b[0] + (float)a[1] * (float)b[1];
#endif
#else
  return c + (float)a[0] * (float)b[0] + (float)a[1] * (float)b[1];
#endif
}

__device__ __forceinline__ float fast_tanh(float x) {
#if defined(__has_builtin)
#if __has_builtin(__builtin_amdgcn_exp2f) && __has_builtin(__builtin_amdgcn_rcpf)
  float e = __builtin_amdgcn_exp2f(x * 2.885390081777927f);
  return 1.0f - 2.0f * __builtin_amdgcn_rcpf(e + 1.0f);
#else
  float e = __builtin_exp2f(x * 2.885390081777927f);
  return 1.0f - 2.0f / (e + 1.0f);
#endif
#else
  float e = exp2f(x * 2.885390081777927f);
  return 1.0f - 2.0f / (e + 1.0f);
#endif
}

__device__ __forceinline__ float u2f(unsigned short u) {
  return (float)__builtin_bit_cast(half_t, u);
}

// 4-way reduce over {l, l^16, l^32, l^48}: 3 independent gathers, 1 DS hop.
__device__ __forceinline__ float red3(float v) {
  float a = __shfl_xor(v, 16);
  float b = __shfl_xor(v, 32);
  float d = __shfl_xor(v, 48);
  return (v + a) + (b + d);
}

// Relaxed workgroup barrier: orders LDS (lgkm), leaves global loads in flight.
__device__ __forceinline__ void wg_barrier_lds() {
  __builtin_amdgcn_sched_barrier(0);
  asm volatile("s_waitcnt lgkmcnt(0)" ::: "memory");
  __builtin_amdgcn_s_barrier();
  __builtin_amdgcn_sched_barrier(0);
}

__device__ __forceinline__ void gl_lds16(const half_t* g, half_t* l) {
  __builtin_amdgcn_global_load_lds(
      (__attribute__((address_space(1))) void*)(void*)g,
      (__attribute__((address_space(3))) void*)(void*)l, 16, 0, 0);
}

// ---------------- cvt kernels (unchanged, verified) ----------------
__global__ void cw_cvt_x(const float* __restrict__ X, half_t* __restrict__ Xh, long n4) {
  long i = (long)blockIdx.x * blockDim.x + threadIdx.x;
  const long stride = (long)gridDim.x * blockDim.x;
  const float4* X4 = (const float4*)X;
  h2* out2 = (h2*)Xh;
  for (; i < n4; i += stride) {
    float4 v = X4[i];
    h2 a; a[0] = (half_t)v.x; a[1] = (half_t)v.y;
    h2 b; b[0] = (half_t)v.z; b[1] = (half_t)v.w;
    out2[2 * i] = a;
    out2[2 * i + 1] = b;
  }
}

__global__ void cw_cvt_wt(const float* __restrict__ W, half_t* __restrict__ WT) {
  int idx = blockIdx.x * 256 + threadIdx.x;  // 131072 total
  int o = idx >> 8, d = idx & 255;
  WT[idx] = (half_t)W[d * 512 + o];
}

// ---------------- x projection (TIME-MAJOR output) ----------------
__global__ __launch_bounds__(256) void cw_xproj(const half_t* __restrict__ Xh,
                                                const half_t* __restrict__ WT,
                                                const float* __restrict__ bias,
                                                half_t* __restrict__ xout) {
  const int mod = blockIdx.y;
  const int Ti = 2048 >> mod;
  const long Mi = (long)64 * Ti;
  const long m0r = (long)blockIdx.x * 256;
  if (m0r >= Mi) return;
  __shared__ alignas(16) half_t Bs[64 * 256];
  __shared__ alignas(16) half_t As[256 * 64];
  const int tid = threadIdx.x;
  const int wv = tid >> 6, l = tid & 63;
  const int lr = l & 15, lk = (l >> 4) * 8;
  const int shf = 11 - mod;

#pragma unroll
  for (int it = 0; it < 8; ++it) {
    int slot = it * 256 + tid;
    int n = slot >> 5, kc = slot & 31;
    gl_lds16(WT + ((mod << 6) + n) * 256 + kc * 8, Bs + slot * 8);
  }

  f4 acc[4][4];
#pragma unroll
  for (int a = 0; a < 4; ++a)
#pragma unroll
    for (int bq = 0; bq < 4; ++bq) acc[a][bq] = f4{0.f, 0.f, 0.f, 0.f};

  for (int kt = 0; kt < 4; ++kt) {
#pragma unroll
    for (int it = 0; it < 8; ++it) {
      int slot = it * 256 + tid;
      int r = slot >> 3, kc = slot & 7;
      long m = m0r + r;
      long g = (m >> shf) * 2048 + ((m & (long)(Ti - 1)) << mod);
      gl_lds16(Xh + g * 256 + kt * 64 + kc * 8, As + slot * 8);
    }
    __syncthreads();
#pragma unroll
    for (int ks = 0; ks < 2; ++ks) {
      h8 af[4], bf[4];
#pragma unroll
      for (int mi = 0; mi < 4; ++mi)
        af[mi] = *(const h8*)&As[(wv * 64 + mi * 16 + lr) * 64 + ks * 32 + lk];
#pragma unroll
      for (int ni = 0; ni < 4; ++ni)
        bf[ni] = *(const h8*)&Bs[(ni * 16 + lr) * 256 + kt * 64 + ks * 32 + lk];
#pragma unroll
      for (int mi = 0; mi < 4; ++mi)
#pragma unroll
        for (int ni = 0; ni < 4; ++ni)
          acc[mi][ni] = __builtin_amdgcn_mfma_f32_16x16x32_f16(af[mi], bf[ni], acc[mi][ni], 0, 0, 0);
    }
    __syncthreads();
  }

  const long xb = 16777216L - (16777216L >> mod);
  // TIME-MAJOR write: element (b, t, n) -> xb + (b*64+n)*Ti + t
#pragma unroll
  for (int ni = 0; ni < 4; ++ni) {
    int n = ni * 16 + lr;
    float bv = bias[(mod << 6) + n];
#pragma unroll
    for (int mi = 0; mi < 4; ++mi) {
      f4 cf = acc[mi][ni];
#pragma unroll
      for (int q = 0; q < 4; ++q) {
        long m = m0r + wv * 64 + mi * 16 + (l >> 4) * 4 + q;
        long bidx = m >> shf;
        long trow = m & (long)(Ti - 1);
        xout[xb + (bidx * 64 + n) * (long)Ti + trow] = (half_t)(cf[q] + bv);
      }
    }
  }
}

// ---------------- scan round 14 (R12 + time-major packed x) ----------------
template <int PAIR>
__device__ __forceinline__ void scan_role(
    const unsigned short* __restrict__ xb16,
    const float* __restrict__ Wf, const float* __restrict__ Ws,
    float* __restrict__ out, half_t (*hbuf)[512], int b) {
  constexpr int P4Fv[4] = {64, 56, 48, 40};
  constexpr int HBFv[4] = {0, 32, 64, 96};
  constexpr int P4Sv[4] = {16, 24, 32, 8};
  constexpr int HBSv[4] = {192, 160, 128, 224};
  constexpr int SSHv[4] = {6, 5, 4, 7};
  constexpr long FXBv[4] = {0L, 8388608L, 12582912L, 14680064L};
  constexpr long SXBv[4] = {16515072L, 16252928L, 15728640L, 16646144L};
  constexpr int FBASEv[4] = {0, 64, 128, 192};
  constexpr int SBASEv[4] = {384, 320, 256, 448};
  constexpr int P4F = P4Fv[PAIR], HBF = HBFv[PAIR];
  constexpr int P4S = P4Sv[PAIR], HBS = HBSv[PAIR], SSH = SSHv[PAIR];
  constexpr int FB = FBASEv[PAIR], SB = SBASEv[PAIR];
  constexpr int SROWS = 2048 >> SSH;
  constexpr int SMASK = (1 << SSH) - 1;
  constexpr int PEXPF = PAIR;            // fast module period exponent
  constexpr int TRF = 2048 >> PEXPF;     // fast x rows per (b,col)

  const int tid = threadIdx.x;
  const int wv = tid >> 6, l = tid & 63;
  const int half = wv & 1;
  const int q = l >> 4;
  const int cl = l & 15;
  const int colA = 32 * half + cl;
  const int colB = colA + 16;
  const int sg01 = q & 1;
  const bool ownFast = (l < 32);
  const int ownCol = 32 * half + 16 * sg01 + cl;

  // ---- weights (all registers, static indices; identical to R12) ----
  h2 wfA[P4F], wfB[P4F], wsA[P4S], wsB[P4S];
  if constexpr (PAIR == 0) {
#pragma unroll
    for (int g = 0; g < 16; ++g) {
      const int gg = (g + 2 * q) & 15;
#pragma unroll
      for (int j = 0; j < 4; ++j) {
        int pr = (q << 6) + gg * 4 + j;
        wfA[g * 4 + j] = h2{(half_t)Wf[(2 * pr) * 64 + colA], (half_t)Wf[(2 * pr + 1) * 64 + colA]};
        wfB[g * 4 + j] = h2{(half_t)Wf[(2 * pr) * 64 + colB], (half_t)Wf[(2 * pr + 1) * 64 + colB]};
      }
    }
  } else {
#pragma unroll
    for (int p = 0; p < P4F; ++p) {
      int pr = q * P4F + p;
      wfA[p] = h2{(half_t)Wf[(2 * pr) * 64 + colA], (half_t)Wf[(2 * pr + 1) * 64 + colA]};
      wfB[p] = h2{(half_t)Wf[(2 * pr) * 64 + colB], (half_t)Wf[(2 * pr + 1) * 64 + colB]};
    }
  }
#pragma unroll
  for (int p = 0; p < P4S; ++p) {
    int pr = q * P4S + p;
    wsA[p] = h2{(half_t)Ws[(2 * pr) * 64 + colA], (half_t)Ws[(2 * pr + 1) * 64 + colA]};
    wsB[p] = h2{(half_t)Ws[(2 * pr) * 64 + colB], (half_t)Ws[(2 * pr + 1) * 64 + colB]};
  }

  hbuf[0][tid] = (half_t)0.f;
  hbuf[1][tid] = (half_t)0.f;

  // ---- time-major x: 8-event chunks, 2-chunk double buffer ----
  constexpr int MYROWS_F = TRF, MYROWS_S = SROWS;
  const unsigned long long* xq = (const unsigned long long*)(
      ownFast ? (xb16 + FXBv[PAIR] + ((long)b * 64 + ownCol) * MYROWS_F)
              : (xb16 + SXBv[PAIR] + ((long)b * 64 + ownCol) * MYROWS_S));
  const int myRows = ownFast ? MYROWS_F : MYROWS_S;
  unsigned long long cLo = xq[0], cHi = xq[1];   // chunk 0 (events 0..7)
  unsigned long long nLo = xq[2], nHi = xq[3];   // chunk 1 (events 8..15)

  float hs = 0.f;
  __syncthreads();

  auto stepf = [&](auto offc, int t, const half_t* hin, half_t* hout) {
    constexpr int OFF = decltype(offc)::value;
    const h2* hin2 = (const h2*)hin;
    constexpr bool FACT = (PAIR == 0) || (PAIR == 1 && (OFF & 1) == 0) ||
                          (PAIR >= 2 && OFF == 0);
    float vA = 0.f, vB = 0.f, vSA = 0.f, vSB = 0.f;
    bool fup = false;
    if constexpr (FACT) {
      if constexpr (PAIR == 3) fup = ((t & 7) == 0);
      else fup = true;
      if (fup) {
        float a0 = 0.f, a1 = 0.f, a2 = 0.f, a3 = 0.f;
        float b0 = 0.f, b1 = 0.f, b2 = 0.f, b3 = 0.f;
        if constexpr (PAIR == 0) {
          const h2* hp = hin2 + (q << 6);
#pragma unroll
          for (int g = 0; g < 16; ++g) {
            const int gg = (g + 2 * q) & 15;  // runtime LDS index only
            h2 h0 = hp[gg * 4 + 0], h1 = hp[gg * 4 + 1];
            h2 h2v = hp[gg * 4 + 2], h3 = hp[gg * 4 + 3];
            a0 = dot2f(h0, wfA[g * 4 + 0], a0); b0 = dot2f(h0, wfB[g * 4 + 0], b0);
            a1 = dot2f(h1, wfA[g * 4 + 1], a1); b1 = dot2f(h1, wfB[g * 4 + 1], b1);
            a2 = dot2f(h2v, wfA[g * 4 + 2], a2); b2 = dot2f(h2v, wfB[g * 4 + 2], b2);
            a3 = dot2f(h3, wfA[g * 4 + 3], a3); b3 = dot2f(h3, wfB[g * 4 + 3], b3);
          }
        } else {
          const h2* hp = hin2 + HBF + q * P4F;
#pragma unroll
          for (int p = 0; p < P4F; p += 4) {
            h2 h0 = hp[p], h1 = hp[p + 1], h2v = hp[p + 2], h3 = hp[p + 3];
            a0 = dot2f(h0, wfA[p + 0], a0); b0 = dot2f(h0, wfB[p + 0], b0);
            a1 = dot2f(h1, wfA[p + 1], a1); b1 = dot2f(h1, wfB[p + 1], b1);
            a2 = dot2f(h2v, wfA[p + 2], a2); b2 = dot2f(h2v, wfB[p + 2], b2);
            a3 = dot2f(h3, wfA[p + 3], a3); b3 = dot2f(h3, wfB[p + 3], b3);
          }
        }
        vA = red3((a0 + a1) + (a2 + a3));
        vB = red3((b0 + b1) + (b2 + b3));
      }
    }
    bool sup = false;
    if constexpr (OFF == 0) {
      sup = ((t & SMASK) == 0);
      if (sup) {
        float a0 = 0.f, a1 = 0.f, a2 = 0.f, a3 = 0.f;
        float b0 = 0.f, b1 = 0.f, b2 = 0.f, b3 = 0.f;
        const h2* hp = hin2 + HBS + q * P4S;
#pragma unroll
        for (int p = 0; p < P4S; p += 4) {
          h2 h0 = hp[p], h1 = hp[p + 1], h2v = hp[p + 2], h3 = hp[p + 3];
          a0 = dot2f(h0, wsA[p + 0], a0); b0 = dot2f(h0, wsB[p + 0], b0);
          a1 = dot2f(h1, wsA[p + 1], a1); b1 = dot2f(h1, wsB[p + 1], b1);
          a2 = dot2f(h2v, wsA[p + 2], a2); b2 = dot2f(h2v, wsB[p + 2], b2);
          a3 = dot2f(h3, wsA[p + 3], a3); b3 = dot2f(h3, wsB[p + 3], b3);
        }
        vSA = red3((a0 + a1) + (a2 + a3));
        vSB = red3((b0 + b1) + (b2 + b3));
      }
    }
    // ---- owner phase: 1 col per lane; packed-x extract at update ----
    bool myUpd = ownFast ? fup : sup;
    float mySum = ownFast ? (sg01 ? vB : vA) : (sg01 ? vSB : vSA);
    const int tact = t + OFF;
    const int e = ownFast ? (tact >> PEXPF) : (t >> SSH);
    const int k = e & 7;
    unsigned long long w = (k & 4) ? cHi : cLo;
    float xv = u2f((unsigned short)(w >> ((k & 3) * 16)));
    float s = myUpd ? (mySum + xv) : hs;
    hs = fast_tanh(s);
    hout[(ownFast ? FB : SB) + ownCol] = (half_t)hs;
    if (myUpd && k == 7) {
      cLo = nLo; cHi = nHi;
      int nc = (e >> 3) + 2;
      if (nc * 8 < myRows) {
        nLo = xq[nc * 2];
        nHi = xq[nc * 2 + 1];
      }
    }
    wg_barrier_lds();
  };

  for (int t = 0; t < 2048; t += 4) {
    stepf(std::integral_constant<int, 0>{}, t, hbuf[0], hbuf[1]);
    stepf(std::integral_constant<int, 1>{}, t, hbuf[1], hbuf[0]);
    stepf(std::integral_constant<int, 2>{}, t, hbuf[0], hbuf[1]);
    stepf(std::integral_constant<int, 3>{}, t, hbuf[1], hbuf[0]);
  }

  out[((long)b << 9) + (ownFast ? FB : SB) + ownCol] = hs;
}

__global__ __launch_bounds__(512, 1) void cw_scan14(
    const half_t* __restrict__ xbuf,
    const float* __restrict__ Wc0, const float* __restrict__ Wc1,
    const float* __restrict__ Wc2, const float* __restrict__ Wc3,
    const float* __restrict__ Wc4, const float* __restrict__ Wc5,
    const float* __restrict__ Wc6, const float* __restrict__ Wc7,
    float* __restrict__ out) {
  __shared__ alignas(16) half_t hbuf[2][512];
  const int b = blockIdx.x;
  const unsigned short* xb16 = (const unsigned short*)xbuf;
  const int pair = threadIdx.x >> 7;  // wave>>1
  if (pair == 0) scan_role<0>(xb16, Wc0, Wc6, out, hbuf, b);
  else if (pair == 1) scan_role<1>(xb16, Wc1, Wc5, out, hbuf, b);
  else if (pair == 2) scan_role<2>(xb16, Wc2, Wc4, out, hbuf, b);
  else scan_role<3>(xb16, Wc3, Wc7, out, hbuf, b);
}

// ---------------- launcher ----------------
extern "C" void kernel_launch(void* const* d_in, const int* in_sizes, int n_in,
                              void* d_out, int out_size, void* d_ws, size_t ws_size,
                              hipStream_t stream) {
  const float* X = (const float*)d_in[0];
  const float* W = (const float*)d_in[1];
  const float* bias = (const float*)d_in[2];
  const float* Wc0 = (const float*)d_in[3];
  const float* Wc1 = (const float*)d_in[4];
  const float* Wc2 = (const float*)d_in[5];
  const float* Wc3 = (const float*)d_in[6];
  const float* Wc4 = (const float*)d_in[7];
  const float* Wc5 = (const float*)d_in[8];
  const float* Wc6 = (const float*)d_in[9];
  const float* Wc7 = (const float*)d_in[10];
  float* out = (float*)d_out;

  half_t* Xh = (half_t*)d_ws;                       // 67,108,864 B
  half_t* WT = (half_t*)((char*)d_ws + 67108864);   //    262,144 B
  half_t* xbuf = (half_t*)((char*)d_ws + 67371008); // 33,423,360 B

  cw_cvt_x<<<4096, 256, 0, stream>>>(X, Xh, 8388608L);
  cw_cvt_wt<<<512, 256, 0, stream>>>(W, WT);
  dim3 g(512, 8);
  cw_xproj<<<g, 256, 0, stream>>>(Xh, WT, bias, xbuf);
  cw_scan14<<<64, 512, 0, stream>>>(xbuf, Wc0, Wc1, Wc2, Wc3, Wc4, Wc5, Wc6, Wc7, out);
}